// Round 1
// baseline (5775.561 us; speedup 1.0000x reference)
//
#include <hip/hip_runtime.h>

#define BATCH 256
#define TT 512
#define CIN 512
#define UU 512
#define ZN 2048
#define BT (BATCH*TT)

typedef __attribute__((ext_vector_type(8))) short short8;
typedef __attribute__((ext_vector_type(4))) float f32x4;

__device__ __forceinline__ short f2bf(float f){
  unsigned u = __float_as_uint(f);
  u += 0x7fffu + ((u >> 16) & 1u);   // round-to-nearest-even
  return (short)(u >> 16);
}
__device__ __forceinline__ float bf2f(short s){
  unsigned u = ((unsigned)(unsigned short)s) << 16;
  return __uint_as_float(u);
}

#define GLD16(g, l) __builtin_amdgcn_global_load_lds( \
    (const __attribute__((address_space(1))) void*)(g), \
    (__attribute__((address_space(3))) void*)(l), 16, 0, 0)

// ---------------- convert x (f32 -> bf16) ----------------
__global__ __launch_bounds__(256) void convert_x_kernel(const float* __restrict__ x,
                                                        short* __restrict__ xb, long n4){
  long stride = (long)gridDim.x * blockDim.x;
  for (long i = (long)blockIdx.x * blockDim.x + threadIdx.x; i < n4; i += stride){
    const float4 v = ((const float4*)x)[i];
    short4 o;
    o.x = f2bf(v.x); o.y = f2bf(v.y); o.z = f2bf(v.z); o.w = f2bf(v.w);
    ((short4*)xb)[i] = o;
  }
}

// ---------------- transpose wx/wh: [512][2048] f32 -> [2048][512] bf16 ----------------
__global__ __launch_bounds__(256) void transpose_w_kernel(
    const float* __restrict__ wx, const float* __restrict__ wh,
    short* __restrict__ wxt, short* __restrict__ wht){
  const float* src = blockIdx.z ? wh : wx;
  short* dst = blockIdx.z ? wht : wxt;
  __shared__ float tile[32][33];
  const int nt = blockIdx.x << 5;   // 0..2047 (col tile of src)
  const int kt = blockIdx.y << 5;   // 0..511  (row tile of src)
  const int tx = threadIdx.x & 31, ty = threadIdx.x >> 5;  // 32x8
  #pragma unroll
  for (int i = 0; i < 32; i += 8)
    tile[ty+i][tx] = src[(long)(kt+ty+i)*ZN + nt+tx];
  __syncthreads();
  #pragma unroll
  for (int i = 0; i < 32; i += 8)
    dst[(long)(nt+ty+i)*512 + kt+tx] = f2bf(tile[tx][ty+i]);
}

// ---------------- xpart GEMM: x_bf[BT][512] @ wx^T -> xpart[BT][2048] bf16 (+bias) ----------------
// m97-style: 128x128 tile, 4 waves (2x2), K-step 32, global_load_lds width 16.
__global__ __launch_bounds__(256) void gemm_xpart_kernel(
    const short* __restrict__ A, const short* __restrict__ Bt,
    const float* __restrict__ bias, short* __restrict__ Co){
  __shared__ short As[128*32];
  __shared__ short Bs[128*32];
  const int tid = threadIdx.x;
  const int lane = tid & 63;
  const int wave = tid >> 6;
  const int wm = wave & 1, wn = wave >> 1;
  const long m0 = (long)blockIdx.y * 128;
  const long n0 = (long)blockIdx.x * 128;
  f32x4 acc[4][4] = {};
  const int srow = tid >> 2;   // 0..63
  const int sseg = tid & 3;
  const long aoff = (m0 + srow) * 512 + sseg * 8;
  const long boff = (n0 + srow) * 512 + sseg * 8;
  short* ldsa = &As[tid * 8];
  short* ldsb = &Bs[tid * 8];
  for (int k0 = 0; k0 < 512; k0 += 32){
    __syncthreads();
    GLD16(A + aoff + k0, ldsa);
    GLD16(A + aoff + 64*512 + k0, ldsa + 2048);
    GLD16(Bt + boff + k0, ldsb);
    GLD16(Bt + boff + 64*512 + k0, ldsb + 2048);
    __syncthreads();
    const int kb = (lane >> 4) * 8;
    short8 af[4], bf[4];
    #pragma unroll
    for (int mi = 0; mi < 4; mi++) af[mi] = *(const short8*)&As[(wm*64 + mi*16 + (lane&15))*32 + kb];
    #pragma unroll
    for (int ni = 0; ni < 4; ni++) bf[ni] = *(const short8*)&Bs[(wn*64 + ni*16 + (lane&15))*32 + kb];
    #pragma unroll
    for (int mi = 0; mi < 4; mi++)
      #pragma unroll
      for (int ni = 0; ni < 4; ni++)
        acc[mi][ni] = __builtin_amdgcn_mfma_f32_16x16x32_bf16(af[mi], bf[ni], acc[mi][ni], 0, 0, 0);
  }
  #pragma unroll
  for (int ni = 0; ni < 4; ni++){
    const long col = n0 + wn*64 + ni*16 + (lane & 15);
    const float bv = bias[col];
    #pragma unroll
    for (int mi = 0; mi < 4; mi++){
      const long row = m0 + wm*64 + mi*16 + ((lane >> 4) << 2);
      #pragma unroll
      for (int r = 0; r < 4; r++)
        Co[(row + r)*ZN + col] = f2bf(acc[mi][ni][r] + bv);
    }
  }
}

// ---------------- one LSTM timestep ----------------
// grid 128 = 4 batch-groups x 32 U-slices; block 256 (4 waves of 16 rows each).
// z-slice per WG: rows rb..rb+64, cols {512g + uc .. +16} for g=0..3.
__global__ __launch_bounds__(256) void lstm_step_kernel(
    const short* __restrict__ xpart, const float* __restrict__ dones,
    const short* __restrict__ wht, const short* __restrict__ hprev,
    short* __restrict__ hnext, float* __restrict__ cstate,
    float* __restrict__ out, int t){
  __shared__ short whB[64*520];   // [64 z-cols][512+8 pad] (B^T layout)
  __shared__ short hA[64*136];    // [64 rows][128+8 pad] K-chunk
  const int tid = threadIdx.x;
  const int lane = tid & 63;
  const int wave = tid >> 6;
  const int ug = blockIdx.x & 31;
  const int bg = blockIdx.x >> 5;
  const int rb = bg << 6;          // batch row base
  const int uc = ug << 4;          // U-col base
  // stage wh slice (once): whB row v = gate (v>>4), col (v&15)
  {
    const int v = tid >> 2;
    const int g = v >> 4, j = v & 15;
    const short* src = wht + (long)(512*g + uc + j) * 512;
    short* dst = &whB[v * 520];
    #pragma unroll
    for (int i = 0; i < 16; i++){
      const int s = (tid & 3) + (i << 2);
      *(short8*)(dst + s*8) = *(const short8*)(src + s*8);
    }
  }
  f32x4 acc[4] = {};
  const int arow = lane & 15;
  for (int kc = 0; kc < 4; kc++){
    __syncthreads();
    {
      const int v = tid >> 2;
      const short* src = hprev + (long)(rb + v)*512 + kc*128 + (tid & 3)*32;
      short* dst = &hA[v*136 + (tid & 3)*32];
      #pragma unroll
      for (int i = 0; i < 4; i++)
        *(short8*)(dst + i*8) = *(const short8*)(src + i*8);
    }
    __syncthreads();
    #pragma unroll
    for (int ks = 0; ks < 4; ks++){
      const int kb = ks*32 + ((lane >> 4) << 3);
      const short8 a = *(const short8*)&hA[(wave*16 + arow)*136 + kb];
      #pragma unroll
      for (int g = 0; g < 4; g++){
        const short8 b = *(const short8*)&whB[(g*16 + arow)*520 + kc*128 + kb];
        acc[g] = __builtin_amdgcn_mfma_f32_16x16x32_bf16(a, b, acc[g], 0, 0, 0);
      }
    }
  }
  // epilogue: z = xpart(+bias) + keep*(h@wh); gates; update c,h; write xs (+ final s)
  const int lcol = lane & 15;
  const int ucol = uc + lcol;
  const int rbase = rb + wave*16 + ((lane >> 4) << 2);
  #pragma unroll
  for (int r = 0; r < 4; r++){
    const int row = rbase + r;
    const float keep = 1.0f - dones[(long)row*TT + t];
    const float cold = cstate[(long)row*UU + ucol] * keep;
    const long xrow = (long)row*TT + t;
    float z[4];
    #pragma unroll
    for (int g = 0; g < 4; g++)
      z[g] = bf2f(xpart[xrow*ZN + g*512 + ucol]) + keep*acc[g][r];
    const float gi = 1.0f/(1.0f + __expf(-z[0]));
    const float gf = 1.0f/(1.0f + __expf(-z[1]));
    const float go = 1.0f/(1.0f + __expf(-z[2]));
    const float gu = tanhf(z[3]);
    const float cn = gf*cold + gi*gu;
    const float hn = go * tanhf(cn);
    cstate[(long)row*UU + ucol] = cn;
    hnext[(long)row*UU + ucol] = f2bf(hn);
    out[(long)row*TT*UU + (long)t*UU + ucol] = hn;
    if (t == TT-1){
      float* s = out + (long)BATCH*TT*UU;
      s[(long)row*2*UU + ucol] = cn;
      s[(long)row*2*UU + UU + ucol] = hn;
    }
  }
}

extern "C" void kernel_launch(void* const* d_in, const int* in_sizes, int n_in,
                              void* d_out, int out_size, void* d_ws, size_t ws_size,
                              hipStream_t stream){
  const float* x     = (const float*)d_in[0];
  const float* dones = (const float*)d_in[1];
  const float* wx    = (const float*)d_in[2];
  const float* wh    = (const float*)d_in[3];
  const float* b     = (const float*)d_in[4];
  float* out = (float*)d_out;
  char* ws = (char*)d_ws;
  // workspace layout (~645 MiB total)
  short* x_bf  = (short*)(ws);                    // 134,217,728 B
  short* wx_t  = (short*)(ws + 134217728L);       //   2,097,152 B
  short* wh_t  = (short*)(ws + 136314880L);       //   2,097,152 B
  short* xpart = (short*)(ws + 138412032L);       // 536,870,912 B
  short* h0    = (short*)(ws + 675282944L);       //     262,144 B
  short* h1    = (short*)(ws + 675545088L);       //     262,144 B
  float* cst   = (float*)(ws + 675807232L);       //     524,288 B

  hipMemsetAsync(h0, 0, 262144, stream);
  hipMemsetAsync(cst, 0, 524288, stream);
  convert_x_kernel<<<2048, 256, 0, stream>>>(x, x_bf, (long)BT*CIN/4);
  transpose_w_kernel<<<dim3(64,16,2), 256, 0, stream>>>(wx, wh, wx_t, wh_t);
  gemm_xpart_kernel<<<dim3(16,1024), 256, 0, stream>>>(x_bf, wx_t, b, xpart);
  for (int t = 0; t < TT; t++){
    short* hp = (t & 1) ? h1 : h0;
    short* hn = (t & 1) ? h0 : h1;
    lstm_step_kernel<<<128, 256, 0, stream>>>(xpart, dones, wh_t, hp, hn, cst, out, t);
  }
}

// Round 2
// 2871.960 us; speedup vs baseline: 2.0110x; 2.0110x over previous
//
#include <hip/hip_runtime.h>

#define BATCH 256
#define TT 512
#define CIN 512
#define UU 512
#define ZN 2048
#define BT (BATCH*TT)
#define NBG 16
#define NCG 32

typedef __attribute__((ext_vector_type(8))) short short8;
typedef __attribute__((ext_vector_type(4))) float f32x4;

__device__ __forceinline__ short f2bf(float f){
  unsigned u = __float_as_uint(f);
  u += 0x7fffu + ((u >> 16) & 1u);   // round-to-nearest-even
  return (short)(u >> 16);
}
__device__ __forceinline__ float bf2f(unsigned short s){
  unsigned u = ((unsigned)s) << 16;
  return __uint_as_float(u);
}

#define GLD16(g, l) __builtin_amdgcn_global_load_lds( \
    (const __attribute__((address_space(1))) void*)(g), \
    (__attribute__((address_space(3))) void*)(l), 16, 0, 0)

// coherent (device-scope, MALL) 16B load with immediate offset
#define CLOAD(dst, p, OFFSTR) asm volatile( \
    "global_load_dwordx4 %0, %1, off offset:" OFFSTR " sc0 sc1" \
    : "=v"(dst) : "v"(p) : "memory")

__device__ __forceinline__ void st_coh_u16(void* p, unsigned v){
  asm volatile("global_store_short %0, %1, off sc0 sc1" :: "v"(p), "v"(v) : "memory");
}

__device__ __forceinline__ float sigm(float x){ return 1.0f/(1.0f + __expf(-x)); }
__device__ __forceinline__ float tanh_fast(float x){ return 1.0f - 2.0f/(1.0f + __expf(2.0f*x)); }

// ---------------- convert x [B][T][C] f32 -> x_tb [(t*B+b)][C] bf16 ----------------
__global__ __launch_bounds__(256) void convert_x_kernel(const float* __restrict__ x,
                                                        short* __restrict__ xb){
  const long total = (long)TT*BATCH*64;   // 8-elem chunks
  const long stride = (long)gridDim.x * blockDim.x;
  for (long i = (long)blockIdx.x * blockDim.x + threadIdx.x; i < total; i += stride){
    const int c8 = (int)(i & 63);
    const long tb = i >> 6;
    const int b = (int)(tb & (BATCH-1));
    const int t = (int)(tb >> 8);
    const float* src = x + ((long)b*TT + t)*CIN + c8*8;
    const float4 v0 = *(const float4*)(src);
    const float4 v1 = *(const float4*)(src + 4);
    short8 o;
    o[0]=f2bf(v0.x); o[1]=f2bf(v0.y); o[2]=f2bf(v0.z); o[3]=f2bf(v0.w);
    o[4]=f2bf(v1.x); o[5]=f2bf(v1.y); o[6]=f2bf(v1.z); o[7]=f2bf(v1.w);
    *(short8*)(xb + i*8) = o;
  }
}

// ---------------- transpose wx/wh: [512][2048] f32 -> [2048][512] bf16 ----------------
__global__ __launch_bounds__(256) void transpose_w_kernel(
    const float* __restrict__ wx, const float* __restrict__ wh,
    short* __restrict__ wxt, short* __restrict__ wht){
  const float* src = blockIdx.z ? wh : wx;
  short* dst = blockIdx.z ? wht : wxt;
  __shared__ float tile[32][33];
  const int nt = blockIdx.x << 5;
  const int kt = blockIdx.y << 5;
  const int tx = threadIdx.x & 31, ty = threadIdx.x >> 5;
  #pragma unroll
  for (int i = 0; i < 32; i += 8)
    tile[ty+i][tx] = src[(long)(kt+ty+i)*ZN + nt+tx];
  __syncthreads();
  #pragma unroll
  for (int i = 0; i < 32; i += 8)
    dst[(long)(nt+ty+i)*512 + kt+tx] = f2bf(tile[tx][ty+i]);
}

// ---------------- xpart GEMM: x_tb[BT][512] @ wx^T -> xpart[BT][2048] bf16 (+bias) ----------------
__global__ __launch_bounds__(256) void gemm_xpart_kernel(
    const short* __restrict__ A, const short* __restrict__ Bt,
    const float* __restrict__ bias, short* __restrict__ Co){
  __shared__ short As[128*32];
  __shared__ short Bs[128*32];
  const int tid = threadIdx.x;
  const int lane = tid & 63;
  const int wave = tid >> 6;
  const int wm = wave & 1, wn = wave >> 1;
  const long m0 = (long)blockIdx.y * 128;
  const long n0 = (long)blockIdx.x * 128;
  f32x4 acc[4][4] = {};
  const int srow = tid >> 2;
  const int sseg = tid & 3;
  const long aoff = (m0 + srow) * 512 + sseg * 8;
  const long boff = (n0 + srow) * 512 + sseg * 8;
  short* ldsa = &As[tid * 8];
  short* ldsb = &Bs[tid * 8];
  for (int k0 = 0; k0 < 512; k0 += 32){
    __syncthreads();
    GLD16(A + aoff + k0, ldsa);
    GLD16(A + aoff + 64*512 + k0, ldsa + 2048);
    GLD16(Bt + boff + k0, ldsb);
    GLD16(Bt + boff + 64*512 + k0, ldsb + 2048);
    __syncthreads();
    const int kb = (lane >> 4) * 8;
    short8 af[4], bf[4];
    #pragma unroll
    for (int mi = 0; mi < 4; mi++) af[mi] = *(const short8*)&As[(wm*64 + mi*16 + (lane&15))*32 + kb];
    #pragma unroll
    for (int ni = 0; ni < 4; ni++) bf[ni] = *(const short8*)&Bs[(wn*64 + ni*16 + (lane&15))*32 + kb];
    #pragma unroll
    for (int mi = 0; mi < 4; mi++)
      #pragma unroll
      for (int ni = 0; ni < 4; ni++)
        acc[mi][ni] = __builtin_amdgcn_mfma_f32_16x16x32_bf16(af[mi], bf[ni], acc[mi][ni], 0, 0, 0);
  }
  #pragma unroll
  for (int ni = 0; ni < 4; ni++){
    const long col = n0 + wn*64 + ni*16 + (lane & 15);
    const float bv = bias[col];
    #pragma unroll
    for (int mi = 0; mi < 4; mi++){
      const long row = m0 + wm*64 + mi*16 + ((lane >> 4) << 2);
      #pragma unroll
      for (int r = 0; r < 4; r++)
        Co[(row + r)*ZN + col] = f2bf(acc[mi][ni][r] + bv);
    }
  }
}

// ---------------- persistent LSTM recurrence ----------------
// 512 one-wave WGs: bg = blockIdx&15 (16 batch rows), cg = blockIdx>>4 (16 u-cols).
// wh slice (64 z-cols x 512 K, XOR-swizzled) LDS-resident; c in registers;
// h ping-pongs through device-coherent (sc0 sc1) global loads/stores; per-bg
// 32-WG atomic barrier per step. LDS = exactly 64 KiB => 2 blocks/CU capacity
// => all 512 WGs co-resident regardless of dispatch order.
__global__ __launch_bounds__(64) void lstm_persist_kernel(
    const short* __restrict__ xpart, const float* __restrict__ dones,
    const short* __restrict__ wht, short* __restrict__ hb0,
    short* __restrict__ hb1, unsigned* __restrict__ ctr,
    float* __restrict__ out){
  __shared__ short whB[64*512];
  const int lane = threadIdx.x;
  const int bg = blockIdx.x & (NBG-1);
  const int cg = blockIdx.x >> 4;
  const int rb = bg << 4;
  const int uc = cg << 4;
  // ---- stage wh slice into LDS (swizzled), one z-col per lane ----
  {
    const int v = lane;                       // z-col 0..63 (gate v>>4, ucol v&15)
    const short* src = wht + ((long)((v>>4)*512 + uc + (v&15)))*512;
    #pragma unroll
    for (int s = 0; s < 64; s++){
      short8 val = *(const short8*)(src + s*8);
      const int db = (((v<<10) + (s<<4)) ^ ((v&3)<<4));
      *(short8*)((char*)whB + db) = val;
    }
  }
  __syncthreads();
  const int j = lane & 15;
  const int hq = lane >> 4;                    // 0..3
  int bb[4];
  #pragma unroll
  for (int g = 0; g < 4; g++)
    bb[g] = ((g*16 + j) << 10) + ((hq ^ (j & 3)) << 4);
  const short* habase0 = hb0 + (long)(rb + j)*UU + hq*8;
  const short* habase1 = hb1 + (long)(rb + j)*UU + hq*8;
  unsigned* myctr = ctr + bg*32;
  const unsigned short* xp16 = (const unsigned short*)xpart;
  float c[4] = {0.f,0.f,0.f,0.f};
  float hnl[4];
  unsigned short xp[4][4];
  float dn[4];
  // prefetch xpart/dones for t=0
  {
    const long xb = ((long)0*BATCH + rb)*ZN + uc + j;
    #pragma unroll
    for (int r = 0; r < 4; r++){
      const int lr = hq*4 + r;
      dn[r] = dones[(long)(rb+lr)*TT + 0];
      #pragma unroll
      for (int g = 0; g < 4; g++)
        xp[r][g] = xp16[xb + (long)lr*ZN + (g<<9)];
    }
  }
  for (int t = 0; t < TT; t++){
    const short* hsrc = (t & 1) ? habase1 : habase0;
    short* hnxt = (t & 1) ? hb0 : hb1;
    short8 a[16];
    CLOAD(a[0],  hsrc, "0");   CLOAD(a[1],  hsrc, "64");
    CLOAD(a[2],  hsrc, "128"); CLOAD(a[3],  hsrc, "192");
    CLOAD(a[4],  hsrc, "256"); CLOAD(a[5],  hsrc, "320");
    CLOAD(a[6],  hsrc, "384"); CLOAD(a[7],  hsrc, "448");
    CLOAD(a[8],  hsrc, "512"); CLOAD(a[9],  hsrc, "576");
    CLOAD(a[10], hsrc, "640"); CLOAD(a[11], hsrc, "704");
    CLOAD(a[12], hsrc, "768"); CLOAD(a[13], hsrc, "832");
    CLOAD(a[14], hsrc, "896"); CLOAD(a[15], hsrc, "960");
    asm volatile("s_waitcnt vmcnt(0)" ::: "memory");
    __builtin_amdgcn_sched_barrier(0);
    f32x4 acc[4] = {};
    #pragma unroll
    for (int kc = 0; kc < 16; kc++){
      #pragma unroll
      for (int g = 0; g < 4; g++){
        const short8 bfrag = *(const short8*)((const char*)whB + (bb[g] + (kc<<6)));
        acc[g] = __builtin_amdgcn_mfma_f32_16x16x32_bf16(a[kc], bfrag, acc[g], 0, 0, 0);
      }
    }
    // ---- gates / state update (fully lane-local) ----
    #pragma unroll
    for (int r = 0; r < 4; r++){
      const int lr = hq*4 + r;
      const int row = rb + lr;
      const float keep = 1.0f - dn[r];
      const float cold = c[r] * keep;
      const float z0 = bf2f(xp[r][0]) + keep*acc[0][r];
      const float z1 = bf2f(xp[r][1]) + keep*acc[1][r];
      const float z2 = bf2f(xp[r][2]) + keep*acc[2][r];
      const float z3 = bf2f(xp[r][3]) + keep*acc[3][r];
      const float gi = sigm(z0);
      const float gf = sigm(z1);
      const float go = sigm(z2);
      const float gu = tanh_fast(z3);
      const float cn = gf*cold + gi*gu;
      const float hn = go * tanh_fast(cn);
      c[r] = cn;
      hnl[r] = hn;
      st_coh_u16(hnxt + (long)row*UU + uc + j, (unsigned)(unsigned short)f2bf(hn));
      out[(long)row*TT*UU + (long)t*UU + uc + j] = hn;
    }
    if (t == TT-1){
      float* s = out + (long)BATCH*TT*UU;
      #pragma unroll
      for (int r = 0; r < 4; r++){
        const int row = rb + hq*4 + r;
        s[(long)row*2*UU + uc + j] = c[r];
        s[(long)row*2*UU + UU + uc + j] = hnl[r];
      }
    } else {
      asm volatile("s_waitcnt vmcnt(0)" ::: "memory");   // h stores globally visible
      if (lane == 0)
        __hip_atomic_fetch_add(myctr, 1u, __ATOMIC_RELAXED, __HIP_MEMORY_SCOPE_AGENT);
      __builtin_amdgcn_sched_barrier(0);
      // prefetch next step's xpart/dones while waiting
      {
        const long xb = ((long)(t+1)*BATCH + rb)*ZN + uc + j;
        #pragma unroll
        for (int r = 0; r < 4; r++){
          const int lr = hq*4 + r;
          dn[r] = dones[(long)(rb+lr)*TT + (t+1)];
          #pragma unroll
          for (int g = 0; g < 4; g++)
            xp[r][g] = xp16[xb + (long)lr*ZN + (g<<9)];
        }
      }
      if (lane == 0){
        const unsigned tgt = (unsigned)(NCG*(t+1));
        while (__hip_atomic_load(myctr, __ATOMIC_RELAXED, __HIP_MEMORY_SCOPE_AGENT) < tgt)
          __builtin_amdgcn_s_sleep(1);
      }
      __builtin_amdgcn_sched_barrier(0);
      asm volatile("" ::: "memory");
    }
  }
}

extern "C" void kernel_launch(void* const* d_in, const int* in_sizes, int n_in,
                              void* d_out, int out_size, void* d_ws, size_t ws_size,
                              hipStream_t stream){
  const float* x     = (const float*)d_in[0];
  const float* dones = (const float*)d_in[1];
  const float* wx    = (const float*)d_in[2];
  const float* wh    = (const float*)d_in[3];
  const float* b     = (const float*)d_in[4];
  float* out = (float*)d_out;
  char* ws = (char*)d_ws;
  short* x_tb  = (short*)(ws);                    // 134,217,728 B
  short* wx_t  = (short*)(ws + 134217728L);       //   2,097,152 B
  short* wh_t  = (short*)(ws + 136314880L);       //   2,097,152 B
  short* xpart = (short*)(ws + 138412032L);       // 536,870,912 B
  short* hb0   = (short*)(ws + 675282944L);       //     262,144 B
  short* hb1   = (short*)(ws + 675545088L);       //     262,144 B
  unsigned* ctr = (unsigned*)(ws + 675807232L);   //       2,048 B

  hipMemsetAsync(hb0, 0, 262144, stream);
  hipMemsetAsync(ctr, 0, 2048, stream);
  convert_x_kernel<<<2048, 256, 0, stream>>>(x, x_tb);
  transpose_w_kernel<<<dim3(64,16,2), 256, 0, stream>>>(wx, wh, wx_t, wh_t);
  gemm_xpart_kernel<<<dim3(16,1024), 256, 0, stream>>>(x_tb, wx_t, b, xpart);
  lstm_persist_kernel<<<512, 64, 0, stream>>>(xpart, dones, wh_t, hb0, hb1, ctr, out);
}

// Round 3
// 2356.542 us; speedup vs baseline: 2.4509x; 1.2187x over previous
//
#include <hip/hip_runtime.h>

#define BATCH 256
#define TT 512
#define CIN 512
#define UU 512
#define ZN 2048
#define BT (BATCH*TT)
#define NWGPB 16   // WGs per batch-group barrier

typedef __attribute__((ext_vector_type(8))) short short8;
typedef __attribute__((ext_vector_type(4))) float f32x4;

__device__ __forceinline__ short f2bf(float f){
  unsigned u = __float_as_uint(f);
  u += 0x7fffu + ((u >> 16) & 1u);   // round-to-nearest-even
  return (short)(u >> 16);
}
__device__ __forceinline__ float bf2f(unsigned short s){
  unsigned u = ((unsigned)s) << 16;
  return __uint_as_float(u);
}

#define GLD16(g, l) __builtin_amdgcn_global_load_lds( \
    (const __attribute__((address_space(1))) void*)(g), \
    (__attribute__((address_space(3))) void*)(l), 16, 0, 0)

// coherent (device-scope) 16B load with immediate offset
#define CLOAD(dst, p, OFFSTR) asm volatile( \
    "global_load_dwordx4 %0, %1, off offset:" OFFSTR " sc0 sc1" \
    : "=v"(dst) : "v"(p) : "memory")

__device__ __forceinline__ void st_coh_u16(void* p, unsigned v){
  asm volatile("global_store_short %0, %1, off sc0 sc1" :: "v"(p), "v"(v) : "memory");
}

__device__ __forceinline__ float sigm(float x){ return 1.0f/(1.0f + __expf(-x)); }
__device__ __forceinline__ float tanh_fast(float x){ return 1.0f - 2.0f/(1.0f + __expf(2.0f*x)); }

// ---------------- convert x [B][T][C] f32 -> x_tb [(t*B+b)][C] bf16 ----------------
__global__ __launch_bounds__(256) void convert_x_kernel(const float* __restrict__ x,
                                                        short* __restrict__ xb){
  const long total = (long)TT*BATCH*64;   // 8-elem chunks
  const long stride = (long)gridDim.x * blockDim.x;
  for (long i = (long)blockIdx.x * blockDim.x + threadIdx.x; i < total; i += stride){
    const int c8 = (int)(i & 63);
    const long tb = i >> 6;
    const int b = (int)(tb & (BATCH-1));
    const int t = (int)(tb >> 8);
    const float* src = x + ((long)b*TT + t)*CIN + c8*8;
    const float4 v0 = *(const float4*)(src);
    const float4 v1 = *(const float4*)(src + 4);
    short8 o;
    o[0]=f2bf(v0.x); o[1]=f2bf(v0.y); o[2]=f2bf(v0.z); o[3]=f2bf(v0.w);
    o[4]=f2bf(v1.x); o[5]=f2bf(v1.y); o[6]=f2bf(v1.z); o[7]=f2bf(v1.w);
    *(short8*)(xb + i*8) = o;
  }
}

// ---------------- transpose wx/wh: [512][2048] f32 -> [2048][512] bf16 ----------------
__global__ __launch_bounds__(256) void transpose_w_kernel(
    const float* __restrict__ wx, const float* __restrict__ wh,
    short* __restrict__ wxt, short* __restrict__ wht){
  const float* src = blockIdx.z ? wh : wx;
  short* dst = blockIdx.z ? wht : wxt;
  __shared__ float tile[32][33];
  const int nt = blockIdx.x << 5;
  const int kt = blockIdx.y << 5;
  const int tx = threadIdx.x & 31, ty = threadIdx.x >> 5;
  #pragma unroll
  for (int i = 0; i < 32; i += 8)
    tile[ty+i][tx] = src[(long)(kt+ty+i)*ZN + nt+tx];
  __syncthreads();
  #pragma unroll
  for (int i = 0; i < 32; i += 8)
    dst[(long)(nt+ty+i)*512 + kt+tx] = f2bf(tile[tx][ty+i]);
}

// ---------------- xpart GEMM: x_tb[BT][512] @ wx^T -> xpart[BT][2048] bf16 (+bias) ----------------
__global__ __launch_bounds__(256) void gemm_xpart_kernel(
    const short* __restrict__ A, const short* __restrict__ Bt,
    const float* __restrict__ bias, short* __restrict__ Co){
  __shared__ short As[128*32];
  __shared__ short Bs[128*32];
  const int tid = threadIdx.x;
  const int lane = tid & 63;
  const int wave = tid >> 6;
  const int wm = wave & 1, wn = wave >> 1;
  const long m0 = (long)blockIdx.y * 128;
  const long n0 = (long)blockIdx.x * 128;
  f32x4 acc[4][4] = {};
  const int srow = tid >> 2;
  const int sseg = tid & 3;
  const long aoff = (m0 + srow) * 512 + sseg * 8;
  const long boff = (n0 + srow) * 512 + sseg * 8;
  short* ldsa = &As[tid * 8];
  short* ldsb = &Bs[tid * 8];
  for (int k0 = 0; k0 < 512; k0 += 32){
    __syncthreads();
    GLD16(A + aoff + k0, ldsa);
    GLD16(A + aoff + 64*512 + k0, ldsa + 2048);
    GLD16(Bt + boff + k0, ldsb);
    GLD16(Bt + boff + 64*512 + k0, ldsb + 2048);
    __syncthreads();
    const int kb = (lane >> 4) * 8;
    short8 af[4], bf[4];
    #pragma unroll
    for (int mi = 0; mi < 4; mi++) af[mi] = *(const short8*)&As[(wm*64 + mi*16 + (lane&15))*32 + kb];
    #pragma unroll
    for (int ni = 0; ni < 4; ni++) bf[ni] = *(const short8*)&Bs[(wn*64 + ni*16 + (lane&15))*32 + kb];
    #pragma unroll
    for (int mi = 0; mi < 4; mi++)
      #pragma unroll
      for (int ni = 0; ni < 4; ni++)
        acc[mi][ni] = __builtin_amdgcn_mfma_f32_16x16x32_bf16(af[mi], bf[ni], acc[mi][ni], 0, 0, 0);
  }
  #pragma unroll
  for (int ni = 0; ni < 4; ni++){
    const long col = n0 + wn*64 + ni*16 + (lane & 15);
    const float bv = bias[col];
    #pragma unroll
    for (int mi = 0; mi < 4; mi++){
      const long row = m0 + wm*64 + mi*16 + ((lane >> 4) << 2);
      #pragma unroll
      for (int r = 0; r < 4; r++)
        Co[(row + r)*ZN + col] = f2bf(acc[mi][ni][r] + bv);
    }
  }
}

// ---------------- persistent LSTM recurrence ----------------
// 256 WGs x 512 threads: bg = blockIdx&15 (16 batch rows), cg = blockIdx>>4 (32 u-cols).
// 8 waves/WG = col-half (2) x K-slice (4). wh fragments REGISTER-resident
// (loaded once; K-split keeps them at 64 VGPR/wave). Partial z sums exchanged
// via conflict-free LDS; epilogue 1 (row,ucol) per thread; c in registers.
// h ping-pongs via device-coherent (sc0 sc1) loads/stores; per-bg barrier =
// 16 atomics on a counter line + spin on a separate epoch line.
__global__ __launch_bounds__(512, 2) void lstm_persist_kernel(
    const short* __restrict__ xpart, const float* __restrict__ dones,
    const short* __restrict__ wht, short* __restrict__ hb0,
    short* __restrict__ hb1, unsigned* __restrict__ ctr,
    float* __restrict__ out){
  __shared__ float part[8192];   // 32KB: [wv=ks*2+ch][g][lane][r] f32
  const int tid = threadIdx.x;
  const int lane = tid & 63;
  const int wv = tid >> 6;          // 0..7
  const int ch = wv & 1;            // col-half
  const int ks = wv >> 1;           // K-slice 0..3
  const int bg = blockIdx.x & 15;
  const int cg = blockIdx.x >> 4;   // 0..15
  const int rb = bg << 4;           // batch row base
  const int uc = cg << 5;           // u-col base (32 cols per WG)
  const int j = lane & 15;
  const int hq = lane >> 4;

  // ---- loop-invariant B fragments: wht[zcol][k], zcol = g*512+uc+ch*16+j ----
  short8 bfr[4][4];                 // [g][kc2] 64 VGPR
  #pragma unroll
  for (int g = 0; g < 4; g++){
    const short* wsrc = wht + ((long)(g*512 + uc + ch*16 + j))*512 + ks*128 + hq*8;
    #pragma unroll
    for (int kc2 = 0; kc2 < 4; kc2++)
      bfr[g][kc2] = *(const short8*)(wsrc + kc2*32);
  }

  // ---- epilogue thread mapping: one (row,ucol) per thread ----
  const int erow = tid >> 5;        // 0..15
  const int euj  = tid & 31;        // 0..31
  const int eucol = uc + euj;
  const int row  = rb + erow;
  // partials base word for (erow,euj) at ks2=0,g=0:
  const int ebase = (((euj >> 4) * 4) << 8) + (((euj & 15) + ((erow >> 2) << 4)) << 2) + (erow & 3);

  unsigned* cnt   = ctr + bg*64;
  unsigned* epoch = ctr + bg*64 + 32;
  const unsigned short* xp16 = (const unsigned short*)xpart;

  float c = 0.0f;
  float dn;
  unsigned short xp[4];
  // prefetch t=0
  dn = dones[(long)row*TT + 0];
  #pragma unroll
  for (int g = 0; g < 4; g++)
    xp[g] = xp16[((long)0*BATCH + row)*ZN + (g<<9) + eucol];

  for (int t = 0; t < TT; t++){
    const short* hsrc = (t & 1) ? hb1 : hb0;
    short* hdst = (t & 1) ? hb0 : hb1;
    // ---- A fragments: h[rb+j][ks*128 + kc2*32 + hq*8] ----
    const short* ab = hsrc + (long)(rb + j)*UU + ks*128 + hq*8;
    short8 a0, a1, a2, a3;
    CLOAD(a0, ab, "0");
    CLOAD(a1, ab, "64");
    CLOAD(a2, ab, "128");
    CLOAD(a3, ab, "192");
    asm volatile("s_waitcnt vmcnt(0)" ::: "memory");
    __builtin_amdgcn_sched_barrier(0);
    f32x4 acc[4] = {};
    #pragma unroll
    for (int g = 0; g < 4; g++){
      acc[g] = __builtin_amdgcn_mfma_f32_16x16x32_bf16(a0, bfr[g][0], acc[g], 0, 0, 0);
      acc[g] = __builtin_amdgcn_mfma_f32_16x16x32_bf16(a1, bfr[g][1], acc[g], 0, 0, 0);
      acc[g] = __builtin_amdgcn_mfma_f32_16x16x32_bf16(a2, bfr[g][2], acc[g], 0, 0, 0);
      acc[g] = __builtin_amdgcn_mfma_f32_16x16x32_bf16(a3, bfr[g][3], acc[g], 0, 0, 0);
    }
    // ---- write partials (contiguous per wave instruction: conflict-free) ----
    #pragma unroll
    for (int g = 0; g < 4; g++)
      *(f32x4*)&part[((wv*4 + g) << 8) + (lane << 2)] = acc[g];
    __syncthreads();
    // ---- reduce + gates (one output per thread) ----
    float z[4];
    #pragma unroll
    for (int g = 0; g < 4; g++){
      const int b0 = ebase + (g << 8);
      z[g] = part[b0] + part[b0 + 2048] + part[b0 + 4096] + part[b0 + 6144];
    }
    const float keep = 1.0f - dn;
    const float cold = c * keep;
    const float z0 = bf2f(xp[0]) + keep*z[0];
    const float z1 = bf2f(xp[1]) + keep*z[1];
    const float z2 = bf2f(xp[2]) + keep*z[2];
    const float z3 = bf2f(xp[3]) + keep*z[3];
    const float gi = sigm(z0);
    const float gf = sigm(z1);
    const float go = sigm(z2);
    const float gu = tanh_fast(z3);
    const float cn = gf*cold + gi*gu;
    const float hn = go * tanh_fast(cn);
    c = cn;
    out[(long)row*TT*UU + (long)t*UU + eucol] = hn;
    if (t == TT-1){
      float* s = out + (long)BATCH*TT*UU;
      s[(long)row*2*UU + eucol] = cn;
      s[(long)row*2*UU + UU + eucol] = hn;
    } else {
      st_coh_u16(hdst + (long)row*UU + eucol, (unsigned)(unsigned short)f2bf(hn));
      asm volatile("s_waitcnt vmcnt(0)" ::: "memory");   // h (and out) stores complete
      __syncthreads();                                    // all waves' stores drained
      if (tid == 0){
        unsigned old = __hip_atomic_fetch_add(cnt, 1u, __ATOMIC_RELAXED, __HIP_MEMORY_SCOPE_AGENT);
        if (old == (unsigned)(NWGPB*(t+1) - 1))
          __hip_atomic_store(epoch, (unsigned)(t+1), __ATOMIC_RELAXED, __HIP_MEMORY_SCOPE_AGENT);
      }
      // prefetch next step's xpart/dones during the wait
      dn = dones[(long)row*TT + (t+1)];
      #pragma unroll
      for (int g = 0; g < 4; g++)
        xp[g] = xp16[((long)(t+1)*BATCH + row)*ZN + (g<<9) + eucol];
      if (tid == 0){
        while (__hip_atomic_load(epoch, __ATOMIC_RELAXED, __HIP_MEMORY_SCOPE_AGENT) < (unsigned)(t+1))
          __builtin_amdgcn_s_sleep(2);
      }
      __syncthreads();                                    // release: h(t) globally ready
    }
  }
}

extern "C" void kernel_launch(void* const* d_in, const int* in_sizes, int n_in,
                              void* d_out, int out_size, void* d_ws, size_t ws_size,
                              hipStream_t stream){
  const float* x     = (const float*)d_in[0];
  const float* dones = (const float*)d_in[1];
  const float* wx    = (const float*)d_in[2];
  const float* wh    = (const float*)d_in[3];
  const float* b     = (const float*)d_in[4];
  float* out = (float*)d_out;
  char* ws = (char*)d_ws;
  short* x_tb  = (short*)(ws);                    // 134,217,728 B
  short* wx_t  = (short*)(ws + 134217728L);       //   2,097,152 B
  short* wh_t  = (short*)(ws + 136314880L);       //   2,097,152 B
  short* xpart = (short*)(ws + 138412032L);       // 536,870,912 B
  short* hb0   = (short*)(ws + 675282944L);       //     262,144 B
  short* hb1   = (short*)(ws + 675545088L);       //     262,144 B
  unsigned* ctr = (unsigned*)(ws + 675807232L);   //       4,096 B

  hipMemsetAsync(hb0, 0, 262144, stream);
  hipMemsetAsync(ctr, 0, 4096, stream);
  convert_x_kernel<<<2048, 256, 0, stream>>>(x, x_tb);
  transpose_w_kernel<<<dim3(64,16,2), 256, 0, stream>>>(wx, wh, wx_t, wh_t);
  gemm_xpart_kernel<<<dim3(16,1024), 256, 0, stream>>>(x_tb, wx_t, b, xpart);
  lstm_persist_kernel<<<256, 512, 0, stream>>>(xpart, dones, wh_t, hb0, hb1, ctr, out);
}